// Round 7
// baseline (187.296 us; speedup 1.0000x reference)
//
#include <hip/hip_runtime.h>
#include <math.h>
#include <stdint.h>

// ---------------------------------------------------------------------------
// TransformerLayer (Swin-style) on MI355X. FP32 I/O; bf16 MFMA internals.
// B=2, H=W=128, C=128, NS=8 -> 64 windows x 256 tokens; HID=1024.
// R14: eliminate fp32->bf16 activation cast round-trip (50MB): gemm_qkv and
//      fused_ffn read fp32 directly + cvt_pk in regs; prep_all = weight
//      transposes only (112 blocks). attn_msg: K1 staged into Ps region
//      under QK0, V0 issued under QK1 (2 drains hidden, 1 barrier deleted).
// ---------------------------------------------------------------------------

typedef unsigned short u16;
typedef __attribute__((ext_vector_type(8))) short bf16x8;   // 8 bf16 (4 VGPRs)
typedef __attribute__((ext_vector_type(4))) float f32x4;
typedef __attribute__((ext_vector_type(4))) short u16x4;
typedef __attribute__((ext_vector_type(2))) unsigned int u32x2;

__device__ __forceinline__ u16 f2b(float f) {
    unsigned int i = __float_as_uint(f);
    unsigned int r = (i + 0x7fffu + ((i >> 16) & 1u)) >> 16;
    return (u16)r;
}

// pack 8 fp32 (two f32x4) -> bf16x8 via v_cvt_pk_bf16_f32 (RNE, same as f2b)
__device__ __forceinline__ bf16x8 pk8(f32x4 a, f32x4 b) {
    union { bf16x8 v; unsigned u[4]; } r;
    asm("v_cvt_pk_bf16_f32 %0, %1, %2" : "=v"(r.u[0]) : "v"(a[0]), "v"(a[1]));
    asm("v_cvt_pk_bf16_f32 %0, %1, %2" : "=v"(r.u[1]) : "v"(a[2]), "v"(a[3]));
    asm("v_cvt_pk_bf16_f32 %0, %1, %2" : "=v"(r.u[2]) : "v"(b[0]), "v"(b[1]));
    asm("v_cvt_pk_bf16_f32 %0, %1, %2" : "=v"(r.u[3]) : "v"(b[2]), "v"(b[3]));
    return r.v;
}

// gelu via A-S 7.1.28 erf (|eps|<=5e-4): ONE transcendental (rcp).
__device__ __forceinline__ float gelu_e(float x) {
    float y = fabsf(x) * 0.70710678118f;
    float u = fmaf(y, fmaf(y, fmaf(y, fmaf(y, 0.078108f, 0.000972f),
                                   0.230389f), 0.278393f), 1.0f);
    u = u * u; u = u * u;
    float r = __builtin_amdgcn_rcpf(u);
    return fmaxf(x, 0.f) - 0.5f * fabsf(x) * r;
}

// 16B async global->LDS (m97-verified). LDS dest wave-uniform base + lane*16.
__device__ __forceinline__ void cp16(const void* g, void* l) {
    auto* gp = reinterpret_cast<const __attribute__((address_space(1))) unsigned int*>(
        reinterpret_cast<uintptr_t>(g));
    auto* lp = reinterpret_cast<__attribute__((address_space(3))) unsigned int*>(
        reinterpret_cast<uintptr_t>(l));
    __builtin_amdgcn_global_load_lds(gp, lp, 16, 0, 0);
}

// window row (b*16384 + win*256 + t) -> source-order row (b*16384 + h*128 + w)
__device__ __forceinline__ int win_map(int gm) {
    int b = gm >> 14, rr = gm & 16383;
    int win = rr >> 8, t = rr & 255;
    int wi = win >> 3, wj = win & 7, i = t >> 4, j = t & 15;
    int h = (wi * 16 + i + 8) & 127;
    int w = (wj * 16 + j + 8) & 127;
    return (b << 14) + h * 128 + w;
}

// ---------------------------------------------------------------------------
// Fused QKV R14: grid (256, 3). A-fragments read fp32 DIRECTLY from
// source/target and cvt to bf16 in regs (no pre-cast pass). LDS = B (32KB)
// + epilogue overlay -> 3 blocks/CU.
// ---------------------------------------------------------------------------
__global__ __launch_bounds__(256, 3)
void gemm_qkv(const float* __restrict__ srcf, const float* __restrict__ tgtf,
              const u16* __restrict__ Bt, u16* __restrict__ qw,
              u16* __restrict__ kw, u16* __restrict__ vwt)
{
    __shared__ __align__(16) u16 SMEM[17408];   // Bs[4][128][32] | Ts 128x136
    u16* Bs = SMEM;
    u16* Ts = SMEM;

    const int tid = threadIdx.x;
    const int w = tid >> 6, lane = tid & 63;
    const int lm = lane & 15, q = lane >> 4;
    const int wm = w >> 1, wn = w & 1;
    const int m0 = blockIdx.x * 128;
    const int y = blockIdx.y;
    const float* Af = (y == 0) ? srcf : tgtf;

    // ---- stage B (32KB) -> LDS ----
#pragma unroll
    for (int s = 0; s < 4; ++s)
#pragma unroll
        for (int i = 0; i < 2; ++i) {
            int row = w * 32 + i * 16 + (lane >> 2);
            int kc = s * 32 + (lane & 3) * 8;
            cp16(Bt + (size_t)(y * 128 + row) * 128 + kc,
                 (void*)(Bs + (s * 128 + w * 32 + i * 16) * 32));
        }

    // ---- A fragments: fp32 global -> regs -> bf16 (issued before barrier) ----
    bf16x8 af[4][4];
#pragma unroll
    for (int t = 0; t < 4; ++t) {
        const float* ap = Af + (size_t)win_map(m0 + wm * 64 + t * 16 + lm) * 128;
#pragma unroll
        for (int s = 0; s < 4; ++s) {
            f32x4 a = *(const f32x4*)(ap + s * 32 + q * 8);
            f32x4 b = *(const f32x4*)(ap + s * 32 + q * 8 + 4);
            af[t][s] = pk8(a, b);
        }
    }
    __syncthreads();   // B landed

    f32x4 acc[4][4] = {};
    __builtin_amdgcn_s_setprio(1);
#pragma unroll
    for (int s = 0; s < 4; ++s) {
        bf16x8 bfr[4];
#pragma unroll
        for (int t = 0; t < 4; ++t)
            bfr[t] = *(const bf16x8*)(Bs + (s * 128 + wn * 64 + t * 16 + lm) * 32 + q * 8);
#pragma unroll
        for (int mt = 0; mt < 4; ++mt)
#pragma unroll
            for (int nt = 0; nt < 4; ++nt)
                acc[mt][nt] = __builtin_amdgcn_mfma_f32_16x16x32_bf16(
                    af[mt][s], bfr[nt], acc[mt][nt], 0, 0, 0);
    }
    __builtin_amdgcn_s_setprio(0);

    __syncthreads();
#pragma unroll
    for (int mt = 0; mt < 4; ++mt)
#pragma unroll
        for (int nt = 0; nt < 4; ++nt)
#pragma unroll
            for (int r = 0; r < 4; ++r) {
                int rowl = wm * 64 + mt * 16 + q * 4 + r;
                int col = wn * 64 + nt * 16 + lm;
                int idx = (y == 2) ? col * 136 + rowl : rowl * 136 + col;
                Ts[idx] = f2b(acc[mt][nt][r]);
            }
    __syncthreads();
    const int c8 = (tid & 15) * 8;
#pragma unroll
    for (int i = 0; i < 8; ++i) {
        int rr = i * 16 + (tid >> 4);
        bf16x8 t = *(const bf16x8*)(Ts + rr * 136 + c8);
        if (y == 2) {
            int wix = m0 >> 8, tok0 = m0 & 255;   // vwT[(b*64+win)*128+ch][tok]
            *(bf16x8*)(vwt + (size_t)wix * 32768 + (size_t)rr * 256 + tok0 + c8) = t;
        } else {
            u16* Cv = (y == 0) ? qw : kw;
            *(bf16x8*)(Cv + (size_t)(m0 + rr) * 128 + c8) = t;
        }
    }
}

// ---------------------------------------------------------------------------
// Fused attention + msg-proj + LayerNorm (R14 pipeline).
// One block = 64 Q rows of a window; grid 512 (XCD remap). LDS: Ps 33.8KB
// (Q overlay -> K1 overlay -> P -> Ot overlay) + B32 32KB (K0 -> V0 -> V1
// -> Wm). K1 staged under QK0; V0 staged under QK1; 7 barriers.
// ---------------------------------------------------------------------------
__global__ __launch_bounds__(256, 2)
void attn_msg(const u16* __restrict__ qw, const u16* __restrict__ kw,
              const u16* __restrict__ vt, const u16* __restrict__ wmt,
              const float* __restrict__ g, const float* __restrict__ bb,
              u16* __restrict__ msgb)
{
    __shared__ __align__(16) u16 Ps[64 * 264];   // 33.8KB multi-overlay
    __shared__ __align__(16) u16 B32[16384];     // 32KB staging buffer

    const int tid = threadIdx.x, w = tid >> 6, lane = tid & 63;
    const int lm = lane & 15, q = lane >> 4;
    const int l4r = lane >> 2, l4c = (lane & 3) * 8;
    const int bid = blockIdx.x;
    const int qc = bid >> 7;                     // XCD-affinity remap (R12)
    const int gwin = bid & 127;
    const int win = gwin & 63, b = gwin >> 6;
    const int wi = win >> 3, wj = win & 7;
    const int q0 = qc * 64;
    const size_t wbase = (size_t)(b * 64 + win);
    const u16* kwb = kw + wbase * 256 * 128;
    const u16* qwb = qw + wbase * 256 * 128;
    const u16* vtb = vt + wbase * 128 * 256;

    // ---- stage Q (Ps[0:16K], [4 kt][64 row][32]) + K0 (B32) ----
    u16* Qs = Ps;
#pragma unroll
    for (int i = 0; i < 4; ++i)
        cp16(qwb + (size_t)(q0 + w * 16 + l4r) * 128 + i * 32 + l4c,
             (void*)(Qs + (i * 64 + w * 16) * 32));
#pragma unroll
    for (int s = 0; s < 4; ++s)
#pragma unroll
        for (int i = 0; i < 2; ++i) {
            int tok = w * 32 + i * 16 + l4r;
            cp16(kwb + (size_t)tok * 128 + s * 32 + l4c,
                 (void*)(B32 + (s * 128 + w * 32 + i * 16) * 32));
        }
    __syncthreads();                       // [1] Q + K0 landed

    bf16x8 af[4];
#pragma unroll
    for (int kt = 0; kt < 4; ++kt)
        af[kt] = *(const bf16x8*)(Qs + (kt * 64 + w * 16 + lm) * 32 + q * 8);
    __syncthreads();                       // [2] all waves done reading Q

    // ---- stage K1 -> Ps[0:32K] (flies under QK0) ----
#pragma unroll
    for (int ss = 0; ss < 4; ++ss)
#pragma unroll
        for (int i = 0; i < 2; ++i) {
            int tok = 128 + w * 32 + i * 16 + l4r;
            cp16(kwb + (size_t)tok * 128 + ss * 32 + l4c,
                 (void*)(Ps + (ss * 128 + w * 32 + i * 16) * 32));
        }

    f32x4 s[16];
#pragma unroll
    for (int nt = 0; nt < 16; ++nt) { f32x4 z = {0.f, 0.f, 0.f, 0.f}; s[nt] = z; }
    // ---- QK0 from B32 ----
    __builtin_amdgcn_s_setprio(1);
#pragma unroll
    for (int kt = 0; kt < 4; ++kt)
#pragma unroll
        for (int nt = 0; nt < 8; ++nt) {
            bf16x8 bf = *(const bf16x8*)(B32 + (kt * 128 + nt * 16 + lm) * 32 + q * 8);
            s[nt] = __builtin_amdgcn_mfma_f32_16x16x32_bf16(af[kt], bf, s[nt], 0, 0, 0);
        }
    __builtin_amdgcn_s_setprio(0);
    __syncthreads();                       // [3] K1 landed; K0 reads done

    // ---- stage V0 -> B32 (flies under QK1 + softmax) ----
#pragma unroll
    for (int tt = 0; tt < 4; ++tt)
#pragma unroll
        for (int i = 0; i < 2; ++i) {
            int ch = w * 32 + i * 16 + l4r;
            cp16(vtb + (size_t)ch * 256 + tt * 32 + l4c,
                 (void*)(B32 + (tt * 128 + w * 32 + i * 16) * 32));
        }
    // ---- QK1 from Ps(K1) ----
    __builtin_amdgcn_s_setprio(1);
#pragma unroll
    for (int kt = 0; kt < 4; ++kt)
#pragma unroll
        for (int nt = 8; nt < 16; ++nt) {
            bf16x8 bf = *(const bf16x8*)(Ps + (kt * 128 + (nt - 8) * 16 + lm) * 32 + q * 8);
            s[nt] = __builtin_amdgcn_mfma_f32_16x16x32_bf16(af[kt], bf, s[nt], 0, 0, 0);
        }
    __builtin_amdgcn_s_setprio(0);
    __syncthreads();                       // [4] V0 landed; K1 reads done
                                           //     (P may now overwrite Ps)

    // ---- analytic Swin mask + softmax (regs), P -> Ps (intra-wave rows) ----
    int idk[16];
#pragma unroll
    for (int nt = 0; nt < 16; ++nt) {
        int rh = (wi == 7) ? ((nt >= 8) ? 2 : 1) : 0;
        int rw = (wj == 7) ? ((lm >= 8) ? 2 : 1) : 0;
        idk[nt] = rh * 3 + rw;
    }
    const float scale = 0.08838834764831845f;
#pragma unroll
    for (int r = 0; r < 4; ++r) {
        int tq = q0 + w * 16 + q * 4 + r;
        int iq = tq >> 4, jq = tq & 15;
        int rhq = (wi == 7) ? ((iq >= 8) ? 2 : 1) : 0;
        int rwq = (wj == 7) ? ((jq >= 8) ? 2 : 1) : 0;
        int idq = rhq * 3 + rwq;
        float sv[16];
        float mx = -1e30f;
#pragma unroll
        for (int nt = 0; nt < 16; ++nt) {
            float x = s[nt][r] * scale + ((idq != idk[nt]) ? -100.f : 0.f);
            sv[nt] = x; mx = fmaxf(mx, x);
        }
        mx = fmaxf(mx, __shfl_xor(mx, 1));
        mx = fmaxf(mx, __shfl_xor(mx, 2));
        mx = fmaxf(mx, __shfl_xor(mx, 4));
        mx = fmaxf(mx, __shfl_xor(mx, 8));
        float sum = 0.f;
#pragma unroll
        for (int nt = 0; nt < 16; ++nt) { float e = __expf(sv[nt] - mx); sv[nt] = e; sum += e; }
        sum += __shfl_xor(sum, 1);
        sum += __shfl_xor(sum, 2);
        sum += __shfl_xor(sum, 4);
        sum += __shfl_xor(sum, 8);
        float inv = 1.0f / sum;
#pragma unroll
        for (int nt = 0; nt < 16; ++nt)
            Ps[(w * 16 + q * 4 + r) * 264 + nt * 16 + lm] = f2b(sv[nt] * inv);
    }
    // NO barrier: P consumers are intra-wave (rows w*16+lm); B32=V0 stable.

    // ---- PV tok[0,128) ----
    f32x4 o[8];
#pragma unroll
    for (int nt = 0; nt < 8; ++nt) { f32x4 z = {0.f, 0.f, 0.f, 0.f}; o[nt] = z; }
    __builtin_amdgcn_s_setprio(1);
#pragma unroll
    for (int tt = 0; tt < 4; ++tt) {
        bf16x8 pf = *(const bf16x8*)(Ps + (w * 16 + lm) * 264 + tt * 32 + q * 8);
#pragma unroll
        for (int nt = 0; nt < 8; ++nt) {
            bf16x8 vf = *(const bf16x8*)(B32 + (tt * 128 + nt * 16 + lm) * 32 + q * 8);
            o[nt] = __builtin_amdgcn_mfma_f32_16x16x32_bf16(pf, vf, o[nt], 0, 0, 0);
        }
    }
    __builtin_amdgcn_s_setprio(0);
    __syncthreads();                       // [5] V0 reads done
    // ---- stage V1 -> B32 ----
#pragma unroll
    for (int tt = 0; tt < 4; ++tt)
#pragma unroll
        for (int i = 0; i < 2; ++i) {
            int ch = w * 32 + i * 16 + l4r;
            cp16(vtb + (size_t)ch * 256 + 128 + tt * 32 + l4c,
                 (void*)(B32 + (tt * 128 + w * 32 + i * 16) * 32));
        }
    __syncthreads();                       // [6] V1 landed (exposed drain)
    __builtin_amdgcn_s_setprio(1);
#pragma unroll
    for (int tt = 4; tt < 8; ++tt) {
        bf16x8 pf = *(const bf16x8*)(Ps + (w * 16 + lm) * 264 + tt * 32 + q * 8);
#pragma unroll
        for (int nt = 0; nt < 8; ++nt) {
            bf16x8 vf = *(const bf16x8*)(B32 + ((tt - 4) * 128 + nt * 16 + lm) * 32 + q * 8);
            o[nt] = __builtin_amdgcn_mfma_f32_16x16x32_bf16(pf, vf, o[nt], 0, 0, 0);
        }
    }
    __builtin_amdgcn_s_setprio(0);
    __syncthreads();                       // [7] V1 + P reads done

    // ---- stage Wm -> B32; O -> Ot (Ps overlay, intra-wave) ----
#pragma unroll
    for (int ss = 0; ss < 4; ++ss)
#pragma unroll
        for (int i = 0; i < 2; ++i) {
            int n = w * 32 + i * 16 + l4r;
            cp16(wmt + (size_t)n * 128 + ss * 32 + l4c,
                 (void*)(B32 + (ss * 128 + w * 32 + i * 16) * 32));
        }
    u16* Ot = Ps;   // [64][136]
#pragma unroll
    for (int r = 0; r < 4; ++r) {
        int rl = w * 16 + q * 4 + r;
#pragma unroll
        for (int nt = 0; nt < 8; ++nt)
            Ot[rl * 136 + nt * 16 + lm] = f2b(o[nt][r]);
    }
    __syncthreads();                       // Wm landed

    // ---- msg = O @ WmT^T (all-LDS) ----
    f32x4 macc[8];
#pragma unroll
    for (int n2 = 0; n2 < 8; ++n2) { f32x4 z = {0.f, 0.f, 0.f, 0.f}; macc[n2] = z; }
    __builtin_amdgcn_s_setprio(1);
#pragma unroll
    for (int kt = 0; kt < 4; ++kt) {
        bf16x8 paf = *(const bf16x8*)(Ot + (w * 16 + lm) * 136 + kt * 32 + q * 8);
#pragma unroll
        for (int n2 = 0; n2 < 8; ++n2) {
            bf16x8 wf = *(const bf16x8*)(B32 + (kt * 128 + n2 * 16 + lm) * 32 + q * 8);
            macc[n2] = __builtin_amdgcn_mfma_f32_16x16x32_bf16(paf, wf, macc[n2], 0, 0, 0);
        }
    }
    __builtin_amdgcn_s_setprio(0);

    // ---- row LN + store (source-order rows) ----
    float gv[8], bv[8];
#pragma unroll
    for (int n2 = 0; n2 < 8; ++n2) {
        int col = n2 * 16 + lm;
        gv[n2] = g[col]; bv[n2] = bb[col];
    }
#pragma unroll
    for (int r = 0; r < 4; ++r) {
        float s1 = 0.f, s2 = 0.f;
#pragma unroll
        for (int n2 = 0; n2 < 8; ++n2) {
            float v = macc[n2][r];
            s1 += v; s2 += v * v;
        }
        s1 += __shfl_xor(s1, 1); s2 += __shfl_xor(s2, 1);
        s1 += __shfl_xor(s1, 2); s2 += __shfl_xor(s2, 2);
        s1 += __shfl_xor(s1, 4); s2 += __shfl_xor(s2, 4);
        s1 += __shfl_xor(s1, 8); s2 += __shfl_xor(s2, 8);
        float mean = s1 * (1.f / 128.f);
        float var = fmaxf(s2 * (1.f / 128.f) - mean * mean, 0.f);
        float rs = rsqrtf(var + 1e-5f);
        int t = q0 + w * 16 + q * 4 + r;
        int ii = t >> 4, jj = t & 15;
        int h = (wi * 16 + ii + 8) & 127;
        int w2 = (wj * 16 + jj + 8) & 127;
        size_t orow = ((size_t)b * 16384 + h * 128 + w2) * 128;
#pragma unroll
        for (int n2 = 0; n2 < 8; ++n2)
            msgb[orow + n2 * 16 + lm] = f2b((macc[n2][r] - mean) * rs * gv[n2] + bv[n2]);
    }
}

// ---------------------------------------------------------------------------
// FUSED FFN (R11 structure + setprio; R14: src half read fp32 directly).
// Grid 512 (64 rows/block), 512 thr (8 waves), 72KB LDS -> 2 blocks/CU.
// ---------------------------------------------------------------------------
__global__ __launch_bounds__(512, 4)
void fused_ffn(const float* __restrict__ A0f, const u16* __restrict__ A1,
               const u16* __restrict__ W1T, const u16* __restrict__ W2T,
               const float* __restrict__ g, const float* __restrict__ bb,
               const float* __restrict__ resid, float* __restrict__ outv)
{
    __shared__ __align__(16) u16 W1s[16384];    // [8 ks][64 hid][32] 32KB single
    __shared__ __align__(16) u16 W2s[16384];    // [2 buf][2 ks][128 col][32] 32KB
    __shared__ __align__(16) u16 Gs[4096];      // [64 tok][64 k] swizzled 8KB

    const int tid = threadIdx.x;
    const int w = tid >> 6, lane = tid & 63;    // w in 0..7
    const int lm = lane & 15, q = lane >> 4;
    const int l4r = lane >> 2, l4c = (lane & 3) * 8;
    const int wm = w >> 2, wn = w & 3;          // wm: tok-32 half, wn: hid16/col32
    const int m0 = blockIdx.x * 64;

    const u16* w1p = W1T + (size_t)l4r * 256 + w * 32 + l4c;
    const u16* w2p = W2T + (size_t)((w & 3) * 32 + l4r) * 1024 + (w >> 2) * 32 + l4c;
    u16* const w1d = W1s + (w * 64) * 32;
    u16* const w2d0 = W2s + (((w >> 2) * 128 + (w & 3) * 32)) * 32;
    u16* const w2d1 = w2d0 + 8192;

    // ---- A -> regs: src half fp32 -> cvt; msg half bf16 ----
    bf16x8 areg[2][8];
#pragma unroll
    for (int mt = 0; mt < 2; ++mt) {
        const int row = m0 + wm * 32 + mt * 16 + lm;
        const float* ap = A0f + (size_t)row * 128;
#pragma unroll
        for (int ks = 0; ks < 4; ++ks) {
            f32x4 a = *(const f32x4*)(ap + ks * 32 + q * 8);
            f32x4 b = *(const f32x4*)(ap + ks * 32 + q * 8 + 4);
            areg[mt][ks] = pk8(a, b);
        }
#pragma unroll
        for (int ks = 4; ks < 8; ++ks)
            areg[mt][ks] = *(const bf16x8*)(
                A1 + (size_t)row * 128 + (ks & 3) * 32 + q * 8);
    }

    // ---- prologue: stage W1(0) -> W1s, W2(0) -> buf0 ----
#pragma unroll
    for (int i = 0; i < 4; ++i)
        cp16(w1p + (size_t)(i * 16) * 256, w1d + (i * 16) * 32);
#pragma unroll
    for (int i = 0; i < 2; ++i)
        cp16(w2p + (size_t)(i * 16) * 1024, w2d0 + (i * 16) * 32);
    w1p += 16384; w2p += 64;
    __syncthreads();                              // W(0) landed

    f32x4 acc2[2][2] = {};                        // 32x32 out tile per wave
#pragma unroll 2
    for (int c = 0; c < 16; ++c) {
        const int cb = c & 1, nb = cb ^ 1;

        // ---- ffn1(c): W1s + areg -> gelu -> Gs ----
        {
            f32x4 acc1[2] = {};
            __builtin_amdgcn_s_setprio(1);
#pragma unroll
            for (int ks = 0; ks < 8; ++ks) {
                bf16x8 w1f = *(const bf16x8*)(W1s + (ks * 64 + wn * 16 + lm) * 32 + q * 8);
#pragma unroll
                for (int mt = 0; mt < 2; ++mt)
                    acc1[mt] = __builtin_amdgcn_mfma_f32_16x16x32_bf16(
                        w1f, areg[mt][ks], acc1[mt], 0, 0, 0);
            }
            __builtin_amdgcn_s_setprio(0);
#pragma unroll
            for (int mt = 0; mt < 2; ++mt) {
                float g0 = gelu_e(acc1[mt][0]), g1 = gelu_e(acc1[mt][1]);
                float g2 = gelu_e(acc1[mt][2]), g3 = gelu_e(acc1[mt][3]);
                unsigned p0, p1;
                asm("v_cvt_pk_bf16_f32 %0, %1, %2" : "=v"(p0) : "v"(g0), "v"(g1));
                asm("v_cvt_pk_bf16_f32 %0, %1, %2" : "=v"(p1) : "v"(g2), "v"(g3));
                int tok = wm * 32 + mt * 16 + lm;
                int slot = (wn * 2 + (q >> 1)) ^ (tok & 7);
                u32x2 pk; pk[0] = p0; pk[1] = p1;
                *(u32x2*)(Gs + tok * 64 + slot * 8 + (q & 1) * 4) = pk;
            }
        }
        __syncthreads();   // Gs visible; all W1s(c) reads done -> W1s free

        // ---- stage W1(c+1) -> W1s, W2(c+1) -> buf[nb] (lands by next bar) ----
        if (c + 1 < 16) {
#pragma unroll
            for (int i = 0; i < 4; ++i)
                cp16(w1p + (size_t)(i * 16) * 256, w1d + (i * 16) * 32);
            u16* d = nb ? w2d1 : w2d0;
#pragma unroll
            for (int i = 0; i < 2; ++i)
                cp16(w2p + (size_t)(i * 16) * 1024, d + (i * 16) * 32);
        }
        w1p += 16384; w2p += 64;

        // ---- ffn2(c): Gs + W2s[cb] -> acc2 ----
        {
            const u16* W2c = W2s + cb * 8192;
            __builtin_amdgcn_s_setprio(1);
#pragma unroll
            for (int ks = 0; ks < 2; ++ks) {
                bf16x8 pa[2], wf[2];
#pragma unroll
                for (int mt = 0; mt < 2; ++mt) {
                    int tok = wm * 32 + mt * 16 + lm;
                    pa[mt] = *(const bf16x8*)(Gs + tok * 64 + (((ks * 4 + q) ^ (tok & 7)) * 8));
                }
#pragma unroll
                for (int nt = 0; nt < 2; ++nt)
                    wf[nt] = *(const bf16x8*)(W2c + (ks * 128 + wn * 32 + nt * 16 + lm) * 32 + q * 8);
#pragma unroll
                for (int mt = 0; mt < 2; ++mt)
#pragma unroll
                    for (int nt = 0; nt < 2; ++nt)
                        acc2[mt][nt] = __builtin_amdgcn_mfma_f32_16x16x32_bf16(
                            pa[mt], wf[nt], acc2[mt][nt], 0, 0, 0);
            }
            __builtin_amdgcn_s_setprio(0);
        }
        __syncthreads();   // drains vmcnt (W(c+1) landed); Gs reads done
    }

    // ---- LN + residual epilogue (stats exchange overlaid on Gs) ----
    float* stats = (float*)Gs;                   // [64][8] = 2KB
#pragma unroll
    for (int mt = 0; mt < 2; ++mt)
#pragma unroll
        for (int r = 0; r < 4; ++r) {
            float s1 = 0.f, s2 = 0.f;
#pragma unroll
            for (int nt = 0; nt < 2; ++nt) {
                float v = acc2[mt][nt][r];
                s1 += v; s2 += v * v;
            }
            s1 += __shfl_xor(s1, 1); s2 += __shfl_xor(s2, 1);
            s1 += __shfl_xor(s1, 2); s2 += __shfl_xor(s2, 2);
            s1 += __shfl_xor(s1, 4); s2 += __shfl_xor(s2, 4);
            s1 += __shfl_xor(s1, 8); s2 += __shfl_xor(s2, 8);
            if (lm == 0) {
                int row = wm * 32 + mt * 16 + q * 4 + r;
                stats[row * 8 + wn * 2] = s1;
                stats[row * 8 + wn * 2 + 1] = s2;
            }
        }
    __syncthreads();

    float gv[2], bv[2];
#pragma unroll
    for (int nt = 0; nt < 2; ++nt) {
        int col = wn * 32 + nt * 16 + lm;
        gv[nt] = g[col]; bv[nt] = bb[col];
    }
#pragma unroll
    for (int mt = 0; mt < 2; ++mt)
#pragma unroll
        for (int r = 0; r < 4; ++r) {
            int row = wm * 32 + mt * 16 + q * 4 + r;
            f32x4 st0 = *(const f32x4*)(stats + row * 8);
            f32x4 st1 = *(const f32x4*)(stats + row * 8 + 4);
            float s1 = st0[0] + st0[2] + st1[0] + st1[2];
            float s2 = st0[1] + st0[3] + st1[1] + st1[3];
            float mean = s1 * (1.f / 128.f);
            float var = fmaxf(s2 * (1.f / 128.f) - mean * mean, 0.f);
            float rs = rsqrtf(var + 1e-5f);
#pragma unroll
            for (int nt = 0; nt < 2; ++nt) {
                int col = wn * 32 + nt * 16 + lm;
                size_t gi = (size_t)(m0 + row) * 128 + col;
                outv[gi] = (acc2[mt][nt][r] - mean) * rs * gv[nt] + bv[nt] + resid[gi];
            }
        }
}

// ---------------------------------------------------------------------------
// Prep R14: weight transposes only (LDS-tiled, coalesced both directions).
// Tiles: bx 0..15 Wq..Wm (4x4), 16..79 W1 (4x16), 80..111 W2 (16x2).
// ---------------------------------------------------------------------------
__global__ void prep_all(const float* __restrict__ Wq, const float* __restrict__ Wk,
                         const float* __restrict__ Wv, const float* __restrict__ Wm,
                         const float* __restrict__ W1, const float* __restrict__ W2,
                         u16* __restrict__ ws)
{
    __shared__ float T[64][65];
    int bx = blockIdx.x;
    const int t = threadIdx.x;
    const float* sp; u16* dst; int R, C, r0, c0;
    if (bx < 16) {                    // Wq,Wk,Wv,Wm: 128x128
        int m = bx >> 2, tt = bx & 3;
        sp = (m == 0) ? Wq : (m == 1) ? Wk : (m == 2) ? Wv : Wm;
        R = 128; C = 128; r0 = (tt >> 1) * 64; c0 = (tt & 1) * 64;
        dst = ws + m * 16384;
    } else if (bx < 80) {             // W1: 256x1024 -> W1T [1024][256]
        int tt = bx - 16;
        sp = W1; R = 256; C = 1024;
        r0 = (tt >> 4) * 64; c0 = (tt & 15) * 64;
        dst = ws + 65536;
    } else {                          // W2: 1024x128 -> W2T [128][1024]
        int tt = bx - 80;
        sp = W2; R = 1024; C = 128;
        r0 = (tt >> 1) * 64; c0 = (tt & 1) * 64;
        dst = ws + 327680;
    }
#pragma unroll
    for (int i = 0; i < 16; ++i) {    // coalesced fp32 read
        int idx = i * 256 + t, r = idx >> 6, c = idx & 63;
        T[r][c] = sp[(size_t)(r0 + r) * C + c0 + c];
    }
    __syncthreads();
#pragma unroll
    for (int i = 0; i < 16; ++i) {    // transposed LDS read, coalesced bf16 write
        int idx = i * 256 + t, n = idx >> 6, k = idx & 63;
        dst[(size_t)(c0 + n) * R + r0 + k] = f2b(T[k][n]);
    }
}

// ---------------------------------------------------------------------------
// Workspace layout (u16 element offsets)
// ---------------------------------------------------------------------------
#define OFF_WQT  0u            // concat [WqT;WkT;WvT] 3x(128x128)
#define OFF_WMT  49152u
#define OFF_W1T  65536u
#define OFF_W2T  327680u
#define OFF_QW   458752u
#define OFF_KW   4653056u
#define OFF_VWT  8847360u
#define OFF_MSGB 13041664u     // bf16 msg, source-order; ends 17235968

extern "C" void kernel_launch(void* const* d_in, const int* in_sizes, int n_in,
                              void* d_out, int out_size, void* d_ws, size_t ws_size,
                              hipStream_t stream)
{
    (void)in_sizes; (void)n_in; (void)out_size; (void)ws_size;
    const float* source = (const float*)d_in[0];
    const float* target = (const float*)d_in[1];
    const float* Wq = (const float*)d_in[2];
    const float* Wk = (const float*)d_in[3];
    const float* Wv = (const float*)d_in[4];
    const float* Wm = (const float*)d_in[5];
    const float* g1 = (const float*)d_in[6];
    const float* b1 = (const float*)d_in[7];
    const float* W1 = (const float*)d_in[8];
    const float* W2 = (const float*)d_in[9];
    const float* g2 = (const float*)d_in[10];
    const float* b2 = (const float*)d_in[11];
    u16* ws = (u16*)d_ws;
    float* out = (float*)d_out;

    prep_all<<<112, 256, 0, stream>>>(Wq, Wk, Wv, Wm, W1, W2, ws);
    gemm_qkv<<<dim3(256, 3), 256, 0, stream>>>(
        source, target, ws + OFF_WQT,
        ws + OFF_QW, ws + OFF_KW, ws + OFF_VWT);
    attn_msg<<<512, 256, 0, stream>>>(
        ws + OFF_QW, ws + OFF_KW, ws + OFF_VWT, ws + OFF_WMT, g1, b1,
        ws + OFF_MSGB);
    fused_ffn<<<512, 512, 0, stream>>>(
        source, ws + OFF_MSGB, ws + OFF_W1T, ws + OFF_W2T,
        g2, b2, source, out);
}

// Round 8
// 186.838 us; speedup vs baseline: 1.0025x; 1.0025x over previous
//
#include <hip/hip_runtime.h>
#include <math.h>
#include <stdint.h>

// ---------------------------------------------------------------------------
// TransformerLayer (Swin-style) on MI355X. FP32 I/O; bf16 MFMA internals.
// B=2, H=W=128, C=128, NS=8 -> 64 windows x 256 tokens; HID=1024.
// R15: latency-chain cuts. gemm_qkv grid (256,2): y=1 computes K AND V from
//      one tgt A-load (two weight passes). attn_msg: Q frags direct
//      global->reg (no LDS round-trip); K0+K1 staged in ONE drain. fused_ffn
//      A0 reverted to bf16 srcb (R13 form); prep re-adds src cast.
// ---------------------------------------------------------------------------

typedef unsigned short u16;
typedef __attribute__((ext_vector_type(8))) short bf16x8;   // 8 bf16 (4 VGPRs)
typedef __attribute__((ext_vector_type(4))) float f32x4;
typedef __attribute__((ext_vector_type(4))) short u16x4;
typedef __attribute__((ext_vector_type(2))) unsigned int u32x2;

__device__ __forceinline__ u16 f2b(float f) {
    unsigned int i = __float_as_uint(f);
    unsigned int r = (i + 0x7fffu + ((i >> 16) & 1u)) >> 16;
    return (u16)r;
}

// pack 8 fp32 (two f32x4) -> bf16x8 via v_cvt_pk_bf16_f32 (RNE, same as f2b)
__device__ __forceinline__ bf16x8 pk8(f32x4 a, f32x4 b) {
    union { bf16x8 v; unsigned u[4]; } r;
    asm("v_cvt_pk_bf16_f32 %0, %1, %2" : "=v"(r.u[0]) : "v"(a[0]), "v"(a[1]));
    asm("v_cvt_pk_bf16_f32 %0, %1, %2" : "=v"(r.u[1]) : "v"(a[2]), "v"(a[3]));
    asm("v_cvt_pk_bf16_f32 %0, %1, %2" : "=v"(r.u[2]) : "v"(b[0]), "v"(b[1]));
    asm("v_cvt_pk_bf16_f32 %0, %1, %2" : "=v"(r.u[3]) : "v"(b[2]), "v"(b[3]));
    return r.v;
}

// gelu via A-S 7.1.28 erf (|eps|<=5e-4): ONE transcendental (rcp).
__device__ __forceinline__ float gelu_e(float x) {
    float y = fabsf(x) * 0.70710678118f;
    float u = fmaf(y, fmaf(y, fmaf(y, fmaf(y, 0.078108f, 0.000972f),
                                   0.230389f), 0.278393f), 1.0f);
    u = u * u; u = u * u;
    float r = __builtin_amdgcn_rcpf(u);
    return fmaxf(x, 0.f) - 0.5f * fabsf(x) * r;
}

// 16B async global->LDS (m97-verified). LDS dest wave-uniform base + lane*16.
__device__ __forceinline__ void cp16(const void* g, void* l) {
    auto* gp = reinterpret_cast<const __attribute__((address_space(1))) unsigned int*>(
        reinterpret_cast<uintptr_t>(g));
    auto* lp = reinterpret_cast<__attribute__((address_space(3))) unsigned int*>(
        reinterpret_cast<uintptr_t>(l));
    __builtin_amdgcn_global_load_lds(gp, lp, 16, 0, 0);
}

// window row (b*16384 + win*256 + t) -> source-order row (b*16384 + h*128 + w)
__device__ __forceinline__ int win_map(int gm) {
    int b = gm >> 14, rr = gm & 16383;
    int win = rr >> 8, t = rr & 255;
    int wi = win >> 3, wj = win & 7, i = t >> 4, j = t & 15;
    int h = (wi * 16 + i + 8) & 127;
    int w = (wj * 16 + j + 8) & 127;
    return (b << 14) + h * 128 + w;
}

// ---------------------------------------------------------------------------
// Fused QKV R15: grid (256, 2). y=0: Q = srcb@Wq (bf16 A direct->reg).
// y=1: K AND V from ONE tgt fp32 A-load (regs), two weight passes
// (WkT then WvT through the same 32KB Bs buffer); V stored transposed.
// LDS 34.8KB (Bs/Ts overlay) -> 3+ blocks/CU.
// ---------------------------------------------------------------------------
__global__ __launch_bounds__(256, 3)
void gemm_qkv(const u16* __restrict__ srcb, const float* __restrict__ tgtf,
              const u16* __restrict__ Bt, u16* __restrict__ qw,
              u16* __restrict__ kw, u16* __restrict__ vwt)
{
    __shared__ __align__(16) u16 SMEM[17408];   // Bs[4][128][32] | Ts 128x136
    u16* Bs = SMEM;
    u16* Ts = SMEM;

    const int tid = threadIdx.x;
    const int w = tid >> 6, lane = tid & 63;
    const int lm = lane & 15, q = lane >> 4;
    const int wm = w >> 1, wn = w & 1;
    const int m0 = blockIdx.x * 128;
    const int y = blockIdx.y;
    const int c8 = (tid & 15) * 8;

    // ---- stage first weight (WqT or WkT) -> Bs ----
#pragma unroll
    for (int s = 0; s < 4; ++s)
#pragma unroll
        for (int i = 0; i < 2; ++i) {
            int row = w * 32 + i * 16 + (lane >> 2);
            int kc = s * 32 + (lane & 3) * 8;
            cp16(Bt + (size_t)(y * 128 + row) * 128 + kc,
                 (void*)(Bs + (s * 128 + w * 32 + i * 16) * 32));
        }

    // ---- A fragments -> regs ----
    bf16x8 af[4][4];
    if (y == 0) {
#pragma unroll
        for (int t = 0; t < 4; ++t) {
            const u16* ap = srcb + (size_t)win_map(m0 + wm * 64 + t * 16 + lm) * 128;
#pragma unroll
            for (int s = 0; s < 4; ++s)
                af[t][s] = *(const bf16x8*)(ap + s * 32 + q * 8);
        }
    } else {
#pragma unroll
        for (int t = 0; t < 4; ++t) {
            const float* ap = tgtf + (size_t)win_map(m0 + wm * 64 + t * 16 + lm) * 128;
#pragma unroll
            for (int s = 0; s < 4; ++s) {
                f32x4 a = *(const f32x4*)(ap + s * 32 + q * 8);
                f32x4 b = *(const f32x4*)(ap + s * 32 + q * 8 + 4);
                af[t][s] = pk8(a, b);
            }
        }
    }
    __syncthreads();   // weight landed (A drained too)

    // ---- pass 1 MFMA (Q or K) ----
    f32x4 acc[4][4] = {};
    __builtin_amdgcn_s_setprio(1);
#pragma unroll
    for (int s = 0; s < 4; ++s) {
        bf16x8 bfr[4];
#pragma unroll
        for (int t = 0; t < 4; ++t)
            bfr[t] = *(const bf16x8*)(Bs + (s * 128 + wn * 64 + t * 16 + lm) * 32 + q * 8);
#pragma unroll
        for (int mt = 0; mt < 4; ++mt)
#pragma unroll
            for (int nt = 0; nt < 4; ++nt)
                acc[mt][nt] = __builtin_amdgcn_mfma_f32_16x16x32_bf16(
                    af[mt][s], bfr[nt], acc[mt][nt], 0, 0, 0);
    }
    __builtin_amdgcn_s_setprio(0);
    __syncthreads();   // Bs reads done

    // ---- pass 1 epilogue -> Ts -> qw/kw ----
#pragma unroll
    for (int mt = 0; mt < 4; ++mt)
#pragma unroll
        for (int nt = 0; nt < 4; ++nt)
#pragma unroll
            for (int r = 0; r < 4; ++r) {
                int rowl = wm * 64 + mt * 16 + q * 4 + r;
                int col = wn * 64 + nt * 16 + lm;
                Ts[rowl * 136 + col] = f2b(acc[mt][nt][r]);
            }
    __syncthreads();
    {
        u16* Cv = (y == 0) ? qw : kw;
#pragma unroll
        for (int i = 0; i < 8; ++i) {
            int rr = i * 16 + (tid >> 4);
            bf16x8 t = *(const bf16x8*)(Ts + rr * 136 + c8);
            *(bf16x8*)(Cv + (size_t)(m0 + rr) * 128 + c8) = t;
        }
    }

    if (y == 1) {
        __syncthreads();   // Ts reads done -> free for WvT stage
        // ---- stage WvT -> Bs ----
#pragma unroll
        for (int s = 0; s < 4; ++s)
#pragma unroll
            for (int i = 0; i < 2; ++i) {
                int row = w * 32 + i * 16 + (lane >> 2);
                int kc = s * 32 + (lane & 3) * 8;
                cp16(Bt + (size_t)(256 + row) * 128 + kc,
                     (void*)(Bs + (s * 128 + w * 32 + i * 16) * 32));
            }
        __syncthreads();   // WvT landed

        // ---- pass 2 MFMA (V, same A regs) ----
        f32x4 acc2[4][4] = {};
        __builtin_amdgcn_s_setprio(1);
#pragma unroll
        for (int s = 0; s < 4; ++s) {
            bf16x8 bfr[4];
#pragma unroll
            for (int t = 0; t < 4; ++t)
                bfr[t] = *(const bf16x8*)(Bs + (s * 128 + wn * 64 + t * 16 + lm) * 32 + q * 8);
#pragma unroll
            for (int mt = 0; mt < 4; ++mt)
#pragma unroll
                for (int nt = 0; nt < 4; ++nt)
                    acc2[mt][nt] = __builtin_amdgcn_mfma_f32_16x16x32_bf16(
                        af[mt][s], bfr[nt], acc2[mt][nt], 0, 0, 0);
        }
        __builtin_amdgcn_s_setprio(0);
        __syncthreads();   // Bs reads done

        // ---- pass 2 epilogue (transposed) -> Ts -> vwt ----
#pragma unroll
        for (int mt = 0; mt < 4; ++mt)
#pragma unroll
            for (int nt = 0; nt < 4; ++nt)
#pragma unroll
                for (int r = 0; r < 4; ++r) {
                    int rowl = wm * 64 + mt * 16 + q * 4 + r;
                    int col = wn * 64 + nt * 16 + lm;
                    Ts[col * 136 + rowl] = f2b(acc2[mt][nt][r]);
                }
        __syncthreads();
        {
            int wix = m0 >> 8, tok0 = m0 & 255;   // vwT[(b*64+win)*128+ch][tok]
#pragma unroll
            for (int i = 0; i < 8; ++i) {
                int rr = i * 16 + (tid >> 4);
                bf16x8 t = *(const bf16x8*)(Ts + rr * 136 + c8);
                *(bf16x8*)(vwt + (size_t)wix * 32768 + (size_t)rr * 256 + tok0 + c8) = t;
            }
        }
    }
}

// ---------------------------------------------------------------------------
// Fused attention + msg-proj + LayerNorm (R15 pipeline).
// One block = 64 Q rows of a window; grid 512 (XCD remap). Q frags load
// global->reg directly (no LDS). K0->B32 and K1->Ps staged in ONE drain.
// Exposed drains: initial K (1) and V1 only. 7 barriers.
// ---------------------------------------------------------------------------
__global__ __launch_bounds__(256, 2)
void attn_msg(const u16* __restrict__ qw, const u16* __restrict__ kw,
              const u16* __restrict__ vt, const u16* __restrict__ wmt,
              const float* __restrict__ g, const float* __restrict__ bb,
              u16* __restrict__ msgb)
{
    __shared__ __align__(16) u16 Ps[64 * 264];   // K1 buf -> P -> Ot overlays
    __shared__ __align__(16) u16 B32[16384];     // K0 -> V0 -> V1 -> Wm

    const int tid = threadIdx.x, w = tid >> 6, lane = tid & 63;
    const int lm = lane & 15, q = lane >> 4;
    const int l4r = lane >> 2, l4c = (lane & 3) * 8;
    const int bid = blockIdx.x;
    const int qc = bid >> 7;                     // XCD-affinity remap (R12)
    const int gwin = bid & 127;
    const int win = gwin & 63, b = gwin >> 6;
    const int wi = win >> 3, wj = win & 7;
    const int q0 = qc * 64;
    const size_t wbase = (size_t)(b * 64 + win);
    const u16* kwb = kw + wbase * 256 * 128;
    const u16* qwb = qw + wbase * 256 * 128;
    const u16* vtb = vt + wbase * 128 * 256;

    // ---- stage K0 -> B32 and K1 -> Ps (single drain) ----
#pragma unroll
    for (int s = 0; s < 4; ++s)
#pragma unroll
        for (int i = 0; i < 2; ++i) {
            int tok = w * 32 + i * 16 + l4r;
            cp16(kwb + (size_t)tok * 128 + s * 32 + l4c,
                 (void*)(B32 + (s * 128 + w * 32 + i * 16) * 32));
            cp16(kwb + (size_t)(128 + tok) * 128 + s * 32 + l4c,
                 (void*)(Ps + (s * 128 + w * 32 + i * 16) * 32));
        }

    // ---- Q fragments: direct global->reg (L2-hot, layout matches) ----
    bf16x8 af[4];
#pragma unroll
    for (int kt = 0; kt < 4; ++kt)
        af[kt] = *(const bf16x8*)(qwb + (size_t)(q0 + w * 16 + lm) * 128 + kt * 32 + q * 8);
    __syncthreads();                       // [1] K0+K1 landed (Q drained)

    f32x4 s[16];
#pragma unroll
    for (int nt = 0; nt < 16; ++nt) { f32x4 z = {0.f, 0.f, 0.f, 0.f}; s[nt] = z; }
    // ---- QK0 from B32 ----
    __builtin_amdgcn_s_setprio(1);
#pragma unroll
    for (int kt = 0; kt < 4; ++kt)
#pragma unroll
        for (int nt = 0; nt < 8; ++nt) {
            bf16x8 bf = *(const bf16x8*)(B32 + (kt * 128 + nt * 16 + lm) * 32 + q * 8);
            s[nt] = __builtin_amdgcn_mfma_f32_16x16x32_bf16(af[kt], bf, s[nt], 0, 0, 0);
        }
    __builtin_amdgcn_s_setprio(0);
    __syncthreads();                       // [2] K0 reads done

    // ---- stage V0 -> B32 (flies under QK1 + softmax) ----
#pragma unroll
    for (int tt = 0; tt < 4; ++tt)
#pragma unroll
        for (int i = 0; i < 2; ++i) {
            int ch = w * 32 + i * 16 + l4r;
            cp16(vtb + (size_t)ch * 256 + tt * 32 + l4c,
                 (void*)(B32 + (tt * 128 + w * 32 + i * 16) * 32));
        }
    // ---- QK1 from Ps(K1) ----
    __builtin_amdgcn_s_setprio(1);
#pragma unroll
    for (int kt = 0; kt < 4; ++kt)
#pragma unroll
        for (int nt = 8; nt < 16; ++nt) {
            bf16x8 bf = *(const bf16x8*)(Ps + (kt * 128 + (nt - 8) * 16 + lm) * 32 + q * 8);
            s[nt] = __builtin_amdgcn_mfma_f32_16x16x32_bf16(af[kt], bf, s[nt], 0, 0, 0);
        }
    __builtin_amdgcn_s_setprio(0);
    __syncthreads();                       // [3] V0 landed; K1 reads done

    // ---- analytic Swin mask + softmax (regs), P -> Ps (intra-wave rows) ----
    int idk[16];
#pragma unroll
    for (int nt = 0; nt < 16; ++nt) {
        int rh = (wi == 7) ? ((nt >= 8) ? 2 : 1) : 0;
        int rw = (wj == 7) ? ((lm >= 8) ? 2 : 1) : 0;
        idk[nt] = rh * 3 + rw;
    }
    const float scale = 0.08838834764831845f;
#pragma unroll
    for (int r = 0; r < 4; ++r) {
        int tq = q0 + w * 16 + q * 4 + r;
        int iq = tq >> 4, jq = tq & 15;
        int rhq = (wi == 7) ? ((iq >= 8) ? 2 : 1) : 0;
        int rwq = (wj == 7) ? ((jq >= 8) ? 2 : 1) : 0;
        int idq = rhq * 3 + rwq;
        float sv[16];
        float mx = -1e30f;
#pragma unroll
        for (int nt = 0; nt < 16; ++nt) {
            float x = s[nt][r] * scale + ((idq != idk[nt]) ? -100.f : 0.f);
            sv[nt] = x; mx = fmaxf(mx, x);
        }
        mx = fmaxf(mx, __shfl_xor(mx, 1));
        mx = fmaxf(mx, __shfl_xor(mx, 2));
        mx = fmaxf(mx, __shfl_xor(mx, 4));
        mx = fmaxf(mx, __shfl_xor(mx, 8));
        float sum = 0.f;
#pragma unroll
        for (int nt = 0; nt < 16; ++nt) { float e = __expf(sv[nt] - mx); sv[nt] = e; sum += e; }
        sum += __shfl_xor(sum, 1);
        sum += __shfl_xor(sum, 2);
        sum += __shfl_xor(sum, 4);
        sum += __shfl_xor(sum, 8);
        float inv = 1.0f / sum;
#pragma unroll
        for (int nt = 0; nt < 16; ++nt)
            Ps[(w * 16 + q * 4 + r) * 264 + nt * 16 + lm] = f2b(sv[nt] * inv);
    }
    // NO barrier: P consumers are intra-wave (rows w*16+lm); B32=V0 stable.

    // ---- PV tok[0,128) ----
    f32x4 o[8];
#pragma unroll
    for (int nt = 0; nt < 8; ++nt) { f32x4 z = {0.f, 0.f, 0.f, 0.f}; o[nt] = z; }
    __builtin_amdgcn_s_setprio(1);
#pragma unroll
    for (int tt = 0; tt < 4; ++tt) {
        bf16x8 pf = *(const bf16x8*)(Ps + (w * 16 + lm) * 264 + tt * 32 + q * 8);
#pragma unroll
        for (int nt = 0; nt < 8; ++nt) {
            bf16x8 vf = *(const bf16x8*)(B32 + (tt * 128 + nt * 16 + lm) * 32 + q * 8);
            o[nt] = __builtin_amdgcn_mfma_f32_16x16x32_bf16(pf, vf, o[nt], 0, 0, 0);
        }
    }
    __builtin_amdgcn_s_setprio(0);
    __syncthreads();                       // [4] V0 reads done
    // ---- stage V1 -> B32 ----
#pragma unroll
    for (int tt = 0; tt < 4; ++tt)
#pragma unroll
        for (int i = 0; i < 2; ++i) {
            int ch = w * 32 + i * 16 + l4r;
            cp16(vtb + (size_t)ch * 256 + 128 + tt * 32 + l4c,
                 (void*)(B32 + (tt * 128 + w * 32 + i * 16) * 32));
        }
    __syncthreads();                       // [5] V1 landed (exposed drain)
    __builtin_amdgcn_s_setprio(1);
#pragma unroll
    for (int tt = 4; tt < 8; ++tt) {
        bf16x8 pf = *(const bf16x8*)(Ps + (w * 16 + lm) * 264 + tt * 32 + q * 8);
#pragma unroll
        for (int nt = 0; nt < 8; ++nt) {
            bf16x8 vf = *(const bf16x8*)(B32 + ((tt - 4) * 128 + nt * 16 + lm) * 32 + q * 8);
            o[nt] = __builtin_amdgcn_mfma_f32_16x16x32_bf16(pf, vf, o[nt], 0, 0, 0);
        }
    }
    __builtin_amdgcn_s_setprio(0);
    __syncthreads();                       // [6] V1 + P reads done

    // ---- stage Wm -> B32; O -> Ot (Ps overlay, intra-wave) ----
#pragma unroll
    for (int ss = 0; ss < 4; ++ss)
#pragma unroll
        for (int i = 0; i < 2; ++i) {
            int n = w * 32 + i * 16 + l4r;
            cp16(wmt + (size_t)n * 128 + ss * 32 + l4c,
                 (void*)(B32 + (ss * 128 + w * 32 + i * 16) * 32));
        }
    u16* Ot = Ps;   // [64][136]
#pragma unroll
    for (int r = 0; r < 4; ++r) {
        int rl = w * 16 + q * 4 + r;
#pragma unroll
        for (int nt = 0; nt < 8; ++nt)
            Ot[rl * 136 + nt * 16 + lm] = f2b(o[nt][r]);
    }
    __syncthreads();                       // [7] Wm landed

    // ---- msg = O @ WmT^T (all-LDS) ----
    f32x4 macc[8];
#pragma unroll
    for (int n2 = 0; n2 < 8; ++n2) { f32x4 z = {0.f, 0.f, 0.f, 0.f}; macc[n2] = z; }
    __builtin_amdgcn_s_setprio(1);
#pragma unroll
    for (int kt = 0; kt < 4; ++kt) {
        bf16x8 paf = *(const bf16x8*)(Ot + (w * 16 + lm) * 136 + kt * 32 + q * 8);
#pragma unroll
        for (int n2 = 0; n2 < 8; ++n2) {
            bf16x8 wf = *(const bf16x8*)(B32 + (kt * 128 + n2 * 16 + lm) * 32 + q * 8);
            macc[n2] = __builtin_amdgcn_mfma_f32_16x16x32_bf16(paf, wf, macc[n2], 0, 0, 0);
        }
    }
    __builtin_amdgcn_s_setprio(0);

    // ---- row LN + store (source-order rows) ----
    float gv[8], bv[8];
#pragma unroll
    for (int n2 = 0; n2 < 8; ++n2) {
        int col = n2 * 16 + lm;
        gv[n2] = g[col]; bv[n2] = bb[col];
    }
#pragma unroll
    for (int r = 0; r < 4; ++r) {
        float s1 = 0.f, s2 = 0.f;
#pragma unroll
        for (int n2 = 0; n2 < 8; ++n2) {
            float v = macc[n2][r];
            s1 += v; s2 += v * v;
        }
        s1 += __shfl_xor(s1, 1); s2 += __shfl_xor(s2, 1);
        s1 += __shfl_xor(s1, 2); s2 += __shfl_xor(s2, 2);
        s1 += __shfl_xor(s1, 4); s2 += __shfl_xor(s2, 4);
        s1 += __shfl_xor(s1, 8); s2 += __shfl_xor(s2, 8);
        float mean = s1 * (1.f / 128.f);
        float var = fmaxf(s2 * (1.f / 128.f) - mean * mean, 0.f);
        float rs = rsqrtf(var + 1e-5f);
        int t = q0 + w * 16 + q * 4 + r;
        int ii = t >> 4, jj = t & 15;
        int h = (wi * 16 + ii + 8) & 127;
        int w2 = (wj * 16 + jj + 8) & 127;
        size_t orow = ((size_t)b * 16384 + h * 128 + w2) * 128;
#pragma unroll
        for (int n2 = 0; n2 < 8; ++n2)
            msgb[orow + n2 * 16 + lm] = f2b((macc[n2][r] - mean) * rs * gv[n2] + bv[n2]);
    }
}

// ---------------------------------------------------------------------------
// FUSED FFN (R13 form restored: A0 bf16): out = resid + LN(gelu(A@W1)@W2).
// Grid 512 (64 rows/block), 512 thr (8 waves), 72KB LDS -> 2 blocks/CU.
// ---------------------------------------------------------------------------
__global__ __launch_bounds__(512, 4)
void fused_ffn(const u16* __restrict__ A0, const u16* __restrict__ A1,
               const u16* __restrict__ W1T, const u16* __restrict__ W2T,
               const float* __restrict__ g, const float* __restrict__ bb,
               const float* __restrict__ resid, float* __restrict__ outv)
{
    __shared__ __align__(16) u16 W1s[16384];    // [8 ks][64 hid][32] 32KB single
    __shared__ __align__(16) u16 W2s[16384];    // [2 buf][2 ks][128 col][32] 32KB
    __shared__ __align__(16) u16 Gs[4096];      // [64 tok][64 k] swizzled 8KB

    const int tid = threadIdx.x;
    const int w = tid >> 6, lane = tid & 63;    // w in 0..7
    const int lm = lane & 15, q = lane >> 4;
    const int l4r = lane >> 2, l4c = (lane & 3) * 8;
    const int wm = w >> 2, wn = w & 3;          // wm: tok-32 half, wn: hid16/col32
    const int m0 = blockIdx.x * 64;

    const u16* w1p = W1T + (size_t)l4r * 256 + w * 32 + l4c;
    const u16* w2p = W2T + (size_t)((w & 3) * 32 + l4r) * 1024 + (w >> 2) * 32 + l4c;
    u16* const w1d = W1s + (w * 64) * 32;
    u16* const w2d0 = W2s + (((w >> 2) * 128 + (w & 3) * 32)) * 32;
    u16* const w2d1 = w2d0 + 8192;

    // ---- A -> regs (one-time): tokens wm*32+mt*16+lm over K=256 ----
    bf16x8 areg[2][8];
#pragma unroll
    for (int mt = 0; mt < 2; ++mt)
#pragma unroll
        for (int ks = 0; ks < 8; ++ks) {
            const u16* Ab = (ks < 4) ? A0 : A1;
            areg[mt][ks] = *(const bf16x8*)(
                Ab + (size_t)(m0 + wm * 32 + mt * 16 + lm) * 128 + (ks & 3) * 32 + q * 8);
        }

    // ---- prologue: stage W1(0) -> W1s, W2(0) -> buf0 ----
#pragma unroll
    for (int i = 0; i < 4; ++i)
        cp16(w1p + (size_t)(i * 16) * 256, w1d + (i * 16) * 32);
#pragma unroll
    for (int i = 0; i < 2; ++i)
        cp16(w2p + (size_t)(i * 16) * 1024, w2d0 + (i * 16) * 32);
    w1p += 16384; w2p += 64;
    __syncthreads();                              // W(0) landed

    f32x4 acc2[2][2] = {};                        // 32x32 out tile per wave
#pragma unroll 2
    for (int c = 0; c < 16; ++c) {
        const int cb = c & 1, nb = cb ^ 1;

        // ---- ffn1(c): W1s + areg -> gelu -> Gs ----
        {
            f32x4 acc1[2] = {};
            __builtin_amdgcn_s_setprio(1);
#pragma unroll
            for (int ks = 0; ks < 8; ++ks) {
                bf16x8 w1f = *(const bf16x8*)(W1s + (ks * 64 + wn * 16 + lm) * 32 + q * 8);
#pragma unroll
                for (int mt = 0; mt < 2; ++mt)
                    acc1[mt] = __builtin_amdgcn_mfma_f32_16x16x32_bf16(
                        w1f, areg[mt][ks], acc1[mt], 0, 0, 0);
            }
            __builtin_amdgcn_s_setprio(0);
#pragma unroll
            for (int mt = 0; mt < 2; ++mt) {
                float g0 = gelu_e(acc1[mt][0]), g1 = gelu_e(acc1[mt][1]);
                float g2 = gelu_e(acc1[mt][2]), g3 = gelu_e(acc1[mt][3]);
                unsigned p0, p1;
                asm("v_cvt_pk_bf16_f32 %0, %1, %2" : "=v"(p0) : "v"(g0), "v"(g1));
                asm("v_cvt_pk_bf16_f32 %0, %1, %2" : "=v"(p1) : "v"(g2), "v"(g3));
                int tok = wm * 32 + mt * 16 + lm;
                int slot = (wn * 2 + (q >> 1)) ^ (tok & 7);
                u32x2 pk; pk[0] = p0; pk[1] = p1;
                *(u32x2*)(Gs + tok * 64 + slot * 8 + (q & 1) * 4) = pk;
            }
        }
        __syncthreads();   // Gs visible; all W1s(c) reads done -> W1s free

        // ---- stage W1(c+1) -> W1s, W2(c+1) -> buf[nb] (lands by next bar) ----
        if (c + 1 < 16) {
#pragma unroll
            for (int i = 0; i < 4; ++i)
                cp16(w1p + (size_t)(i * 16) * 256, w1d + (i * 16) * 32);
            u16* d = nb ? w2d1 : w2d0;
#pragma unroll
            for (int i = 0; i < 2; ++i)
                cp16(w2p + (size_t)(i * 16) * 1024, d + (i * 16) * 32);
        }
        w1p += 16384; w2p += 64;

        // ---- ffn2(c): Gs + W2s[cb] -> acc2 ----
        {
            const u16* W2c = W2s + cb * 8192;
            __builtin_amdgcn_s_setprio(1);
#pragma unroll
            for (int ks = 0; ks < 2; ++ks) {
                bf16x8 pa[2], wf[2];
#pragma unroll
                for (int mt = 0; mt < 2; ++mt) {
                    int tok = wm * 32 + mt * 16 + lm;
                    pa[mt] = *(const bf16x8*)(Gs + tok * 64 + (((ks * 4 + q) ^ (tok & 7)) * 8));
                }
#pragma unroll
                for (int nt = 0; nt < 2; ++nt)
                    wf[nt] = *(const bf16x8*)(W2c + (ks * 128 + wn * 32 + nt * 16 + lm) * 32 + q * 8);
#pragma unroll
                for (int mt = 0; mt < 2; ++mt)
#pragma unroll
                    for (int nt = 0; nt < 2; ++nt)
                        acc2[mt][nt] = __builtin_amdgcn_mfma_f32_16x16x32_bf16(
                            pa[mt], wf[nt], acc2[mt][nt], 0, 0, 0);
            }
            __builtin_amdgcn_s_setprio(0);
        }
        __syncthreads();   // drains vmcnt (W(c+1) landed); Gs reads done
    }

    // ---- LN + residual epilogue (stats exchange overlaid on Gs) ----
    float* stats = (float*)Gs;                   // [64][8] = 2KB
#pragma unroll
    for (int mt = 0; mt < 2; ++mt)
#pragma unroll
        for (int r = 0; r < 4; ++r) {
            float s1 = 0.f, s2 = 0.f;
#pragma unroll
            for (int nt = 0; nt < 2; ++nt) {
                float v = acc2[mt][nt][r];
                s1 += v; s2 += v * v;
            }
            s1 += __shfl_xor(s1, 1); s2 += __shfl_xor(s2, 1);
            s1 += __shfl_xor(s1, 2); s2 += __shfl_xor(s2, 2);
            s1 += __shfl_xor(s1, 4); s2 += __shfl_xor(s2, 4);
            s1 += __shfl_xor(s1, 8); s2 += __shfl_xor(s2, 8);
            if (lm == 0) {
                int row = wm * 32 + mt * 16 + q * 4 + r;
                stats[row * 8 + wn * 2] = s1;
                stats[row * 8 + wn * 2 + 1] = s2;
            }
        }
    __syncthreads();

    float gv[2], bv[2];
#pragma unroll
    for (int nt = 0; nt < 2; ++nt) {
        int col = wn * 32 + nt * 16 + lm;
        gv[nt] = g[col]; bv[nt] = bb[col];
    }
#pragma unroll
    for (int mt = 0; mt < 2; ++mt)
#pragma unroll
        for (int r = 0; r < 4; ++r) {
            int row = wm * 32 + mt * 16 + q * 4 + r;
            f32x4 st0 = *(const f32x4*)(stats + row * 8);
            f32x4 st1 = *(const f32x4*)(stats + row * 8 + 4);
            float s1 = st0[0] + st0[2] + st1[0] + st1[2];
            float s2 = st0[1] + st0[3] + st1[1] + st1[3];
            float mean = s1 * (1.f / 128.f);
            float var = fmaxf(s2 * (1.f / 128.f) - mean * mean, 0.f);
            float rs = rsqrtf(var + 1e-5f);
#pragma unroll
            for (int nt = 0; nt < 2; ++nt) {
                int col = wn * 32 + nt * 16 + lm;
                size_t gi = (size_t)(m0 + row) * 128 + col;
                outv[gi] = (acc2[mt][nt][r] - mean) * rs * gv[nt] + bv[nt] + resid[gi];
            }
        }
}

// ---------------------------------------------------------------------------
// Prep R15: 112 LDS-tiled weight-transpose blocks + 4096 src-cast blocks.
// ---------------------------------------------------------------------------
__global__ void prep_all(const float* __restrict__ Wq, const float* __restrict__ Wk,
                         const float* __restrict__ Wv, const float* __restrict__ Wm,
                         const float* __restrict__ W1, const float* __restrict__ W2,
                         const float* __restrict__ src, u16* __restrict__ ws,
                         u16* __restrict__ srcb)
{
    int bx = blockIdx.x;
    if (bx < 112) {
        __shared__ float T[64][65];
        const int t = threadIdx.x;
        const float* sp; u16* dst; int R, C, r0, c0;
        if (bx < 16) {                    // Wq,Wk,Wv,Wm: 128x128
            int m = bx >> 2, tt = bx & 3;
            sp = (m == 0) ? Wq : (m == 1) ? Wk : (m == 2) ? Wv : Wm;
            R = 128; C = 128; r0 = (tt >> 1) * 64; c0 = (tt & 1) * 64;
            dst = ws + m * 16384;
        } else if (bx < 80) {             // W1: 256x1024 -> W1T [1024][256]
            int tt = bx - 16;
            sp = W1; R = 256; C = 1024;
            r0 = (tt >> 4) * 64; c0 = (tt & 15) * 64;
            dst = ws + 65536;
        } else {                          // W2: 1024x128 -> W2T [128][1024]
            int tt = bx - 80;
            sp = W2; R = 1024; C = 128;
            r0 = (tt >> 1) * 64; c0 = (tt & 1) * 64;
            dst = ws + 327680;
        }
#pragma unroll
        for (int i = 0; i < 16; ++i) {    // coalesced fp32 read
            int idx = i * 256 + t, r = idx >> 6, c = idx & 63;
            T[r][c] = sp[(size_t)(r0 + r) * C + c0 + c];
        }
        __syncthreads();
#pragma unroll
        for (int i = 0; i < 16; ++i) {    // transposed LDS read, coalesced bf16 write
            int idx = i * 256 + t, n = idx >> 6, k = idx & 63;
            dst[(size_t)(c0 + n) * R + r0 + k] = f2b(T[k][n]);
        }
    } else {
        int idx = (bx - 112) * 256 + threadIdx.x;    // 0..1048575
        int i = idx * 4;
        f32x4 v = *(const f32x4*)(src + i);
        u16x4 o; o[0] = f2b(v[0]); o[1] = f2b(v[1]); o[2] = f2b(v[2]); o[3] = f2b(v[3]);
        *(u16x4*)(srcb + i) = o;
    }
}

// ---------------------------------------------------------------------------
// Workspace layout (u16 element offsets)
// ---------------------------------------------------------------------------
#define OFF_WQT  0u            // concat [WqT;WkT;WvT] 3x(128x128)
#define OFF_WMT  49152u
#define OFF_W1T  65536u
#define OFF_W2T  327680u
#define OFF_SRCB 458752u       // bf16 src 2x16384x128
#define OFF_QW   4653056u
#define OFF_KW   8847360u
#define OFF_VWT  13041664u
#define OFF_MSGB 17235968u     // bf16 msg, source-order; ends 21430272

extern "C" void kernel_launch(void* const* d_in, const int* in_sizes, int n_in,
                              void* d_out, int out_size, void* d_ws, size_t ws_size,
                              hipStream_t stream)
{
    (void)in_sizes; (void)n_in; (void)out_size; (void)ws_size;
    const float* source = (const float*)d_in[0];
    const float* target = (const float*)d_in[1];
    const float* Wq = (const float*)d_in[2];
    const float* Wk = (const float*)d_in[3];
    const float* Wv = (const float*)d_in[4];
    const float* Wm = (const float*)d_in[5];
    const float* g1 = (const float*)d_in[6];
    const float* b1 = (const float*)d_in[7];
    const float* W1 = (const float*)d_in[8];
    const float* W2 = (const float*)d_in[9];
    const float* g2 = (const float*)d_in[10];
    const float* b2 = (const float*)d_in[11];
    u16* ws = (u16*)d_ws;
    float* out = (float*)d_out;

    prep_all<<<4208, 256, 0, stream>>>(Wq, Wk, Wv, Wm, W1, W2, source,
                                       ws, ws + OFF_SRCB);
    gemm_qkv<<<dim3(256, 2), 256, 0, stream>>>(
        ws + OFF_SRCB, target, ws + OFF_WQT,
        ws + OFF_QW, ws + OFF_KW, ws + OFF_VWT);
    attn_msg<<<512, 256, 0, stream>>>(
        ws + OFF_QW, ws + OFF_KW, ws + OFF_VWT, ws + OFF_WMT, g1, b1,
        ws + OFF_MSGB);
    fused_ffn<<<512, 512, 0, stream>>>(
        ws + OFF_SRCB, ws + OFF_MSGB, ws + OFF_W1T, ws + OFF_W2T,
        g2, b2, source, out);
}